// Round 14
// baseline (62347.668 us; speedup 1.0000x reference)
//
#include <hip/hip_runtime.h>
#include <hip/hip_bf16.h>

#define S_ 512
#define B_ 128
#define D_ 128
#define H_ 512
#define NB_ 256

// ---- packed f16 2-plane weight layout: 32 slabs x 316 chunks x 1024 shorts ----
#define SLAB_SHORTS 323584
#define PK_TOT 10354688
#define APLANE 65536
#define ASZ    131072  // 2*APLANE

#define SC1F 4.8828125e-4f          // 2^-11
#define SC2F 2.384185791015625e-7f  // 2^-22

// LDS map (bytes): ldsF scratch 0..8191; 3 stage slots of 32KB at LDSB + t*32768
#define LDSB 8192
#define LDSTOT 106496

typedef short bf16x8 __attribute__((ext_vector_type(8)));
typedef _Float16 f16x8 __attribute__((ext_vector_type(8)));
typedef int i32x4 __attribute__((ext_vector_type(4)));
typedef float f32x4 __attribute__((ext_vector_type(4)));

__device__ __forceinline__ float sigf(float x) { return 1.0f / (1.0f + expf(-x)); }

// plain cached 16B load (weights/x — L2-resident per XCD, never invalidated)
__device__ __forceinline__ i32x4 ldg(const short* p) {
  i32x4 o;
  asm volatile("global_load_dwordx4 %0, %1, off" : "=v"(o) : "v"(p));
  return o;
}
// sc1 coherent 16B load (cross-XCD activations — MALL truth)
__device__ __forceinline__ i32x4 ldgs(const short* p) {
  i32x4 o;
  asm volatile("global_load_dwordx4 %0, %1, off sc1" : "=v"(o) : "v"(p));
  return o;
}
__device__ __forceinline__ unsigned int ldus(const short* p) {
  unsigned int o;
  asm volatile("global_load_ushort %0, %1, off sc1" : "=v"(o) : "v"(p));
  return o;
}
#define VMDRAIN()                                    \
  do {                                               \
    asm volatile("s_waitcnt vmcnt(0)" ::: "memory"); \
    __builtin_amdgcn_sched_barrier(0);               \
  } while (0)

// sc1 write-through store (agent-visible after vmcnt(0); no dirty L2 line)
__device__ __forceinline__ void stg16s(short* p, unsigned int v) {
  asm volatile("global_store_short %0, %1, off sc1" ::"v"(p), "v"(v) : "memory");
}
__device__ __forceinline__ void st2sc(short* buf, int idx, float v) {
  _Float16 h0 = (_Float16)v;
  _Float16 h1 = (_Float16)((v - (float)h0) * 2048.0f);
  stg16s(buf + idx, (unsigned int)__builtin_bit_cast(unsigned short, h0));
  stg16s(buf + idx + APLANE, (unsigned int)__builtin_bit_cast(unsigned short, h1));
}
__device__ __forceinline__ float h2f(unsigned int u) {
  return (float)__builtin_bit_cast(_Float16, (unsigned short)(u & 0xffffu));
}

#define MFMAH(a, b, c) __builtin_amdgcn_mfma_f32_16x16x32_f16(a, b, c, 0, 0, 0)
#define BC16(x) __builtin_bit_cast(f16x8, x)

__device__ __forceinline__ void mac4(f32x4& c0, f32x4& c1, f32x4& c2, const f16x8& a0,
                                     const f16x8& a1, const f16x8& w0, const f16x8& w1) {
  c0 = MFMAH(a0, w0, c0);
  c1 = MFMAH(a0, w1, c1);
  c1 = MFMAH(a1, w0, c1);
  c2 = MFMAH(a1, w1, c2);
}
__device__ __forceinline__ f32x4 fin3(const f32x4& c0, const f32x4& c1,
                                      const f32x4& c2) {
  f32x4 o;
#pragma unroll
  for (int e = 0; e < 4; ++e) o[e] = c0[e] + SC1F * c1[e] + SC2F * c2[e];
  return o;
}

// ---- 4-row stage: one thread stages 1x16B unit per tensor (rows 0..3 of slot;
// rows 4..15 stay zero from the one-time init => MFMA computes zeros there).
__device__ __forceinline__ void stage2s(const short* t0, const short* t1, int row0) {
  extern __shared__ char smem[];
  const int c = (int)threadIdx.x;
  const int pl = c >> 8, u = c & 255, rr = u >> 6, k16 = u & 63;
  const int goff = pl * APLANE + (row0 + rr) * H_ + k16 * 8;
  const int loff = LDSB + pl * 16384 + ((rr * 1024 + k16 * 16) ^ ((rr & 7) << 4));
  i32x4 a = ldgs(t0 + goff);
  i32x4 b = ldgs(t1 + goff);
  VMDRAIN();
  *(i32x4*)(smem + loff) = a;
  *(i32x4*)(smem + 32768 + loff) = b;
}
__device__ __forceinline__ void stage3s(const short* t0, const short* t1,
                                        const short* t2, int row0) {
  extern __shared__ char smem[];
  const int c = (int)threadIdx.x;
  const int pl = c >> 8, u = c & 255, rr = u >> 6, k16 = u & 63;
  const int goff = pl * APLANE + (row0 + rr) * H_ + k16 * 8;
  const int loff = LDSB + pl * 16384 + ((rr * 1024 + k16 * 16) ^ ((rr & 7) << 4));
  i32x4 a = ldgs(t0 + goff);
  i32x4 b = ldgs(t1 + goff);
  i32x4 d = ldgs(t2 + goff);
  VMDRAIN();
  *(i32x4*)(smem + loff) = a;
  *(i32x4*)(smem + 32768 + loff) = b;
  *(i32x4*)(smem + 65536 + loff) = d;
}

// GEMV unit: A from LDS slot (swizzled, rows>=4 zero), W plain global (L2-hot).
__device__ __forceinline__ void unitL(f32x4& c0, f32x4& c1, f32x4& c2, int ldsBase,
                                      int qoff, const short* slabW, int nks, int lo,
                                      int r, int g) {
  extern __shared__ char smem[];
  for (int q = 0; q < nks; q += 4) {
    i32x4 W0[4], W1[4];
#pragma unroll
    for (int u = 0; u < 4; ++u) {
      const short* wp = slabW + (size_t)(q + u) * 1024 + lo;
      W0[u] = ldg(wp);
      W1[u] = ldg(wp + 512);
    }
    bf16x8 A0[4], A1[4];
#pragma unroll
    for (int u = 0; u < 4; ++u) {
      const int ka = ((r * 1024 + (q + qoff + u) * 64 + g * 16) ^ ((r & 7) << 4));
      A0[u] = *(const bf16x8*)(smem + ldsBase + ka);
      A1[u] = *(const bf16x8*)(smem + ldsBase + 16384 + ka);
    }
    VMDRAIN();
#pragma unroll
    for (int u = 0; u < 4; ++u)
      mac4(c0, c1, c2, BC16(A0[u]), BC16(A1[u]), BC16(W0[u]), BC16(W1[u]));
  }
}

// phase-B compute: wave handles 6 chunk-units c=cbase..cbase+5 of [t(0..2)|q(0..15)]
__device__ __forceinline__ void computeB(f32x4& c0, f32x4& c1, f32x4& c2, int cbase,
                                         const short* slabB, int lo, int r, int g) {
  extern __shared__ char smem[];
  i32x4 W0[6], W1[6];
#pragma unroll
  for (int u = 0; u < 6; ++u) {
    const short* wp = slabB + (size_t)(cbase + u) * 1024 + lo;
    W0[u] = ldg(wp);
    W1[u] = ldg(wp + 512);
  }
  bf16x8 A0[6], A1[6];
#pragma unroll
  for (int u = 0; u < 6; ++u) {
    const int c = cbase + u;
    const int t = c >> 4;
    const int q = c & 15;
    const int ka = LDSB + t * 32768 + ((r * 1024 + q * 64 + g * 16) ^ ((r & 7) << 4));
    A0[u] = *(const bf16x8*)(smem + ka);
    A1[u] = *(const bf16x8*)(smem + ka + 16384);
  }
  VMDRAIN();
#pragma unroll
  for (int u = 0; u < 6; ++u)
    mac4(c0, c1, c2, BC16(A0[u]), BC16(A1[u]), BC16(W0[u]), BC16(W1[u]));
}

// x-part (4 kchunks of fp32 x, plain cached, split on the fly)
__device__ __forceinline__ void unitPx(f32x4& c0, f32x4& c1, f32x4& c2,
                                       const float* xRow, const short* slab, int lo) {
  i32x4 W0[4], W1[4];
  f16x8 A0[4], A1[4];
#pragma unroll
  for (int u = 0; u < 4; ++u) {
    const short* wp = slab + (size_t)u * 1024 + lo;
    W0[u] = ldg(wp);
    W1[u] = ldg(wp + 512);
#pragma unroll
    for (int e = 0; e < 8; ++e) {
      float v = xRow[u * 32 + e];
      _Float16 h0 = (_Float16)v;
      A0[u][e] = h0;
      A1[u][e] = (_Float16)((v - (float)h0) * 2048.0f);
    }
  }
  VMDRAIN();
#pragma unroll
  for (int u = 0; u < 4; ++u) mac4(c0, c1, c2, A0[u], A1[u], BC16(W0[u]), BC16(W1[u]));
}

// ---- atomics (agent scope, relaxed, monotonic) ----
__device__ __forceinline__ unsigned int afa(unsigned int* p) {
  return __hip_atomic_fetch_add(p, 1u, __ATOMIC_RELAXED, __HIP_MEMORY_SCOPE_AGENT);
}
__device__ __forceinline__ unsigned int ald(const unsigned int* p) {
  return __hip_atomic_load(p, __ATOMIC_RELAXED, __HIP_MEMORY_SCOPE_AGENT);
}

// global grouped barrier; L1-only invalidate (weights in L2 stay resident).
__device__ __forceinline__ void gbar(unsigned int* ctl, unsigned int t, int grp) {
  asm volatile("s_waitcnt vmcnt(0) lgkmcnt(0)" ::: "memory");  // release sc1 stores
  __syncthreads();
  if (threadIdx.x == 0) {
    unsigned int a = afa(&ctl[grp * 32]);
    if (a == t * 32u - 1u) {
      unsigned int m = afa(&ctl[256]);
      if (m == t * 8u - 1u)
        __hip_atomic_store(&ctl[288], t, __ATOMIC_RELAXED, __HIP_MEMORY_SCOPE_AGENT);
    }
    int guard = 0;
    while (ald(&ctl[288]) < t) {
      __builtin_amdgcn_s_sleep(2);
      if (++guard > (1 << 24)) break;  // bail: wrong answer beats hang
    }
  }
  __syncthreads();
  asm volatile("buffer_inv sc0" ::: "memory");  // L1 only
  __builtin_amdgcn_sched_barrier(0);
}

struct PP {
  const float* x;
  const short* pw;
  short* h0s;
  short* h1s;
  short* xn0;
  short* hn0;
  short* ch0;
  short* xn1;
  short* hn1;
  short* ch1;
  short* o0;
  short* o1;
  const float* bhi0;
  const float* bcho0;
  const float* bhi1;
  const float* bcho1;
  float* out;
  unsigned int* ctl;
};

// Fat-slab partition: cg = bid&7 (col-group of 64 cols = 4 slabs, one per XCD under
// round-robin placement => 2.59MB weight set L2-resident), rt = bid>>3, row0 = rt*4.
// Each phase loops v=0..3 over virtual slabs s = cg*4+v reusing ONE staged 4-row
// activation slice (4x sc1 dedup vs r13). Only g==0 lanes write outputs (rows 0..3).
__global__ __launch_bounds__(512, 1) void eltm_p(PP p) {
  extern __shared__ char smem[];
  float* ldsF = (float*)smem;
  const int tid = threadIdx.x;
  const int lane = tid & 63;
  const int w = tid >> 6;
  const int r = lane & 15;
  const int g = lane >> 4;
  const int lo = r * 32 + g * 8;
  const f32x4 z = {0.f, 0.f, 0.f, 0.f};

  const int bid = blockIdx.x;
  const int cg = bid & 7;
  const int rt = bid >> 3;
  const int row0 = rt * 4;
  const int grp = cg;

  static const int preW[8] = {0, 20480, 40960, 45056, 61440, 94208, 126976, 143360};

  // one-time zero of the 3 stage slots (rows>=4 stay zero forever)
  {
    const i32x4 zz = {0, 0, 0, 0};
    for (int a = tid * 16; a < 3 * 32768; a += 512 * 16)
      *(i32x4*)(smem + LDSB + a) = zz;
  }
  __syncthreads();

  int rowx = row0 + r;
  if (rowx > B_ - 1) rowx = B_ - 1;  // clamp (rows>=4 outputs never written)

  unsigned int bt = 0;
  for (int i = 0; i <= S_; ++i) {
    const int do0 = i < S_;
    const int do1 = i >= 1;
    const float* xr = p.x + ((size_t)i * B_ + rowx) * D_ + g * 8;

    // ================= phase A ================= (h0s slot0, h1s slot1)
    stage2s(p.h0s, p.h1s, row0);
    __syncthreads();
    for (int v = 0; v < 4; ++v) {
      const int s = cg * 4 + v;
      const int n = s * 16 + r;
      const short* slabA = p.pw + (size_t)s * SLAB_SHORTS;
      f32x4 c0 = z, c1 = z, c2 = z;
      f32x4 fin = z;
      switch (w) {
        case 0:
        case 1:
          if (do0) {
            const short* sl = slabA + preW[w];
            unitPx(c0, c1, c2, xr, sl, lo);
            unitL(c0, c1, c2, LDSB, 0, sl + 4096, 16, lo, r, g);
            fin = fin3(c0, c1, c2);
          }
          break;
        case 2:
          if (do0) {
            unitPx(c0, c1, c2, xr, slabA + preW[2], lo);
            fin = fin3(c0, c1, c2);
            if (g == 0)
#pragma unroll
              for (int e = 0; e < 4; ++e)
                st2sc(p.xn0, (row0 + e) * H_ + n, tanhf(fin[e]));
          }
          break;
        case 3:
          if (do0) {
            unitL(c0, c1, c2, LDSB, 0, slabA + preW[3], 16, lo, r, g);
            fin = fin3(c0, c1, c2);
            if (g == 0)
#pragma unroll
              for (int e = 0; e < 4; ++e)
                st2sc(p.hn0, (row0 + e) * H_ + n, tanhf(fin[e]));
          }
          break;
        case 4:
        case 5:
          if (do1) {
            const short* sl = slabA + preW[w];
            unitL(c0, c1, c2, LDSB, 0, sl, 16, lo, r, g);
            unitL(c0, c1, c2, LDSB + 32768, 0, sl + 16384, 16, lo, r, g);
            fin = fin3(c0, c1, c2);
          }
          break;
        case 6:
          if (do1) {
            unitL(c0, c1, c2, LDSB, 0, slabA + preW[6], 16, lo, r, g);
            fin = fin3(c0, c1, c2);
            if (g == 0)
#pragma unroll
              for (int e = 0; e < 4; ++e)
                st2sc(p.xn1, (row0 + e) * H_ + n, tanhf(fin[e]));
          }
          break;
        default:
          if (do1) {
            unitL(c0, c1, c2, LDSB + 32768, 0, slabA + preW[7], 16, lo, r, g);
            fin = fin3(c0, c1, c2);
            if (g == 0)
#pragma unroll
              for (int e = 0; e < 4; ++e)
                st2sc(p.hn1, (row0 + e) * H_ + n, tanhf(fin[e]));
          }
          break;
      }
      if ((w == 1 && do0) || (w == 5 && do1)) {
#pragma unroll
        for (int e = 0; e < 4; ++e)
          ldsF[(w == 5 ? 256 : 0) + (g * 4 + e) * 16 + r] = fin[e];
      }
      __syncthreads();
      if (w == 0 && do0 && g == 0) {
        const float bi = p.bhi0[n], bh = p.bhi0[512 + n];
#pragma unroll
        for (int e = 0; e < 4; ++e) {
          float hgv = ldsF[e * 16 + r];
          st2sc(p.ch0, (row0 + e) * H_ + n, sigf(fin[e] + bi) * tanhf(hgv + bh));
        }
      }
      if (w == 4 && do1 && g == 0) {
        const float bi = p.bhi1[n], bh = p.bhi1[512 + n];
#pragma unroll
        for (int e = 0; e < 4; ++e) {
          float hgv = ldsF[256 + e * 16 + r];
          st2sc(p.ch1, (row0 + e) * H_ + n, sigf(fin[e] + bi) * tanhf(hgv + bh));
        }
      }
      __syncthreads();
    }
    ++bt;
    gbar(p.ctl, bt, grp);

    // ================= phase B ================= (slots: xn,hn,ch; L0 then L1)
    stage3s(p.xn0, p.hn0, p.ch0, row0);
    __syncthreads();
    for (int v = 0; v < 4; ++v) {
      const int s = cg * 4 + v;
      const int n = s * 16 + r;
      if (do0) {
        f32x4 c0 = z, c1 = z, c2 = z;
        computeB(c0, c1, c2, w * 6, p.pw + (size_t)s * SLAB_SHORTS + 156 * 1024, lo, r,
                 g);
        f32x4 fA = fin3(c0, c1, c2);
#pragma unroll
        for (int e = 0; e < 4; ++e) ldsF[w * 256 + (g * 4 + e) * 16 + r] = fA[e];
      }
      __syncthreads();
      if (w == 0 && do0 && g == 0) {
        const float bc = p.bcho0[n];
#pragma unroll
        for (int e = 0; e < 4; ++e) {
          const int q = e * 16 + r;
          float sum = 0.f;
#pragma unroll
          for (int ww = 0; ww < 8; ++ww) sum += ldsF[ww * 256 + q];
          st2sc(p.o0, (row0 + e) * H_ + n, sigf(sum + bc));
        }
      }
      __syncthreads();
    }
    stage3s(p.xn1, p.hn1, p.ch1, row0);
    __syncthreads();
    for (int v = 0; v < 4; ++v) {
      const int s = cg * 4 + v;
      const int n = s * 16 + r;
      if (do1) {
        f32x4 c0 = z, c1 = z, c2 = z;
        computeB(c0, c1, c2, w * 6,
                 p.pw + (size_t)s * SLAB_SHORTS + 156 * 1024 + 49152, lo, r, g);
        f32x4 fA = fin3(c0, c1, c2);
#pragma unroll
        for (int e = 0; e < 4; ++e) ldsF[w * 256 + (g * 4 + e) * 16 + r] = fA[e];
      }
      __syncthreads();
      if (w == 0 && do1 && g == 0) {
        const float bc = p.bcho1[n];
#pragma unroll
        for (int e = 0; e < 4; ++e) {
          const int q = e * 16 + r;
          float sum = 0.f;
#pragma unroll
          for (int ww = 0; ww < 8; ++ww) sum += ldsF[ww * 256 + q];
          st2sc(p.o1, (row0 + e) * H_ + n, sigf(sum + bc));
        }
      }
      __syncthreads();
    }
    ++bt;
    gbar(p.ctl, bt, grp);

    // ================= phase C ================= (o0 slot0, o1 slot1)
    stage2s(p.o0, p.o1, row0);
    __syncthreads();
    for (int v = 0; v < 4; ++v) {
      const int s = cg * 4 + v;
      const int L = s & 1;
      const int ok = L ? do1 : do0;
      const int u = w >> 1;
      const int h = w & 1;
      if (ok) {
        f32x4 c0 = z, c1 = z, c2 = z;
        const short* slab = p.pw + (size_t)s * SLAB_SHORTS + 252 * 1024 +
                            (size_t)u * 16384 + (size_t)h * 8192;
        unitL(c0, c1, c2, LDSB + L * 32768, h * 8, slab, 8, lo, r, g);
        f32x4 fin = fin3(c0, c1, c2);
#pragma unroll
        for (int e = 0; e < 4; ++e) ldsF[w * 256 + (g * 4 + e) * 16 + r] = fin[e];
      }
      __syncthreads();
      if ((w == 0 || w == 4) && ok && g == 0) {
        const int j = (w == 0) ? (s >> 1) : (16 + (s >> 1));
        const int ub = (w == 0) ? 0 : 4;
        const short* xn = L ? p.xn1 : p.xn0;
        const short* hn = L ? p.hn1 : p.hn0;
        const short* ch = L ? p.ch1 : p.ch0;
        short* hs = L ? p.h1s : p.h0s;
        unsigned int dx[8], dh[8], dc[8];
#pragma unroll
        for (int e = 0; e < 4; ++e) {
          const int idx = (row0 + e) * H_ + j * 16 + r;
          dx[e * 2] = ldus(xn + idx);
          dx[e * 2 + 1] = ldus(xn + idx + APLANE);
          dh[e * 2] = ldus(hn + idx);
          dh[e * 2 + 1] = ldus(hn + idx + APLANE);
          dc[e * 2] = ldus(ch + idx);
          dc[e * 2 + 1] = ldus(ch + idx + APLANE);
        }
        VMDRAIN();
#pragma unroll
        for (int e = 0; e < 4; ++e) {
          const int q = e * 16 + r;
          const float av = ldsF[(ub + 0) * 256 + q] + ldsF[(ub + 1) * 256 + q];
          const float bv = ldsF[(ub + 2) * 256 + q] + ldsF[(ub + 3) * 256 + q];
          const float xv = h2f(dx[e * 2]) + h2f(dx[e * 2 + 1]) * SC1F;
          const float hv = h2f(dh[e * 2]) + h2f(dh[e * 2 + 1]) * SC1F;
          const float cv = h2f(dc[e * 2]) + h2f(dc[e * 2 + 1]) * SC1F;
          const int idx = (row0 + e) * H_ + j * 16 + r;
          const float hval = av * xv + bv * hv + (1.f - av - bv) * cv;
          st2sc(hs, idx, hval);
          if (L) p.out[(size_t)(i - 1) * B_ * H_ + idx] = hval;
        }
      }
      __syncthreads();
    }
    ++bt;
    gbar(p.ctl, bt, grp);
  }
}

// ---------------- prologue: repack (r11-validated mapping, UNCHANGED) ----------------
struct WP18 {
  const float* m[18];
};
__global__ void repack(WP18 wp, short* pw) {
  const long long t8 = (long long)blockIdx.x * 256 + threadIdx.x;
  const long long id = t8 * 8;
  if (id >= (long long)PK_TOT) return;
  const int s = (int)(id / SLAB_SHORTS);
  const int rem = (int)(id % SLAB_SHORTS);
  const int c = rem >> 10;
  const int r2 = rem & 1023;
  const int p = r2 >> 9;
  const int q2 = r2 & 511;
  const int rr = q2 >> 5;
  const int gg = (q2 & 31) >> 3;
  const int n0 = s * 16;
  int mat, row, kb;
  if (c < 156) {
    const int segA[9] = {0, 20, 40, 44, 60, 92, 124, 140, 156};
    int sg = 0;
    while (c >= segA[sg + 1]) ++sg;
    const int cl = c - segA[sg];
    const int kin = cl * 32 + gg * 8;
    switch (sg) {
      case 0:
        row = n0 + rr;
        if (kin < 128) { mat = 0; kb = kin; } else { mat = 1; kb = kin - 128; }
        break;
      case 1:
        row = 512 + n0 + rr;
        if (kin < 128) { mat = 0; kb = kin; } else { mat = 1; kb = kin - 128; }
        break;
      case 2: mat = 2; row = n0 + rr; kb = kin; break;
      case 3: mat = 3; row = n0 + rr; kb = kin; break;
      case 4:
        row = n0 + rr;
        if (kin < 512) { mat = 9; kb = kin; } else { mat = 10; kb = kin - 512; }
        break;
      case 5:
        row = 512 + n0 + rr;
        if (kin < 512) { mat = 9; kb = kin; } else { mat = 10; kb = kin - 512; }
        break;
      case 6: mat = 11; row = n0 + rr; kb = kin; break;
      default: mat = 12; row = n0 + rr; kb = kin; break;
    }
  } else if (c < 252) {
    const int cl = c - 156;
    const int L = cl >= 48;
    const int cc = cl - (L ? 48 : 0);
    mat = (L ? 13 : 4) + (cc >> 4);
    row = n0 + rr;
    kb = (cc & 15) * 32 + gg * 8;
  } else {
    const int cc = c - 252;
    const int u = cc >> 4;
    const int L = s & 1;
    const int j = (u < 2) ? (s >> 1) : (16 + (s >> 1));
    mat = (L ? 16 : 7) + (u & 1);
    row = j * 16 + rr;
    kb = (cc & 15) * 32 + gg * 8;
  }
  const int KS = (mat == 0 || mat == 2) ? 128 : 512;
  const float* src = wp.m[mat] + (long long)row * KS + kb;
  bf16x8 o8;
#pragma unroll
  for (int e = 0; e < 8; ++e) {
    float v = src[e];
    _Float16 h0 = (_Float16)v;
    short sv;
    if (p == 0)
      sv = __builtin_bit_cast(short, h0);
    else {
      _Float16 h1 = (_Float16)((v - (float)h0) * 2048.0f);
      sv = __builtin_bit_cast(short, h1);
    }
    o8[e] = sv;
  }
  *(bf16x8*)(pw + id) = o8;
}

// ---------------- final: in-place sinrelu + LayerNorm over H on d_out ----------------
__global__ void eltm_kLN(float* __restrict__ out, const float* __restrict__ g,
                         const float* __restrict__ bta) {
  const int row = blockIdx.x * 4 + (threadIdx.x >> 6);
  const int lane = threadIdx.x & 63;
  float* r = out + (size_t)row * H_;
  float v[8];
  float s = 0.f, s2 = 0.f;
#pragma unroll
  for (int i = 0; i < 8; ++i) {
    float x = r[lane + i * 64];
    float sv = (x >= 0.f) ? (x + sinf(x)) : 0.f;
    v[i] = sv;
    s += sv;
    s2 += sv * sv;
  }
#pragma unroll
  for (int m = 1; m < 64; m <<= 1) {
    s += __shfl_xor(s, m);
    s2 += __shfl_xor(s2, m);
  }
  const float mean = s * (1.f / 512.f);
  const float var = s2 * (1.f / 512.f) - mean * mean;
  const float rstd = rsqrtf(var + 1e-5f);
#pragma unroll
  for (int i = 0; i < 8; ++i) {
    const int c = lane + i * 64;
    r[c] = (v[i] - mean) * rstd * g[c] + bta[c];
  }
}

extern "C" void kernel_launch(void* const* d_in, const int* in_sizes, int n_in,
                              void* d_out, int out_size, void* d_ws, size_t ws_size,
                              hipStream_t stream) {
#define W(i) ((const float*)d_in[i])
  short* pw = (short*)d_ws;
  short* acts = pw + (size_t)PK_TOT;
  short* h0s = acts;
  short* h1s = acts + ASZ;
  short* xn0 = acts + 2 * ASZ;
  short* hn0 = acts + 3 * ASZ;
  short* ch0 = acts + 4 * ASZ;
  short* xn1 = acts + 5 * ASZ;
  short* hn1 = acts + 6 * ASZ;
  short* ch1 = acts + 7 * ASZ;
  short* o0 = acts + 8 * ASZ;
  short* o1 = acts + 9 * ASZ;
  unsigned int* ctl = (unsigned int*)(acts + 10 * (size_t)ASZ);
  float* out = (float*)d_out;

  WP18 wps;
  const int srcIdx[18] = {1,  2,  4,  5,  6,  7,  8,  10, 11,
                          12, 13, 15, 16, 17, 18, 19, 21, 22};
  for (int i = 0; i < 18; ++i) wps.m[i] = W(srcIdx[i]);

  repack<<<PK_TOT / 8 / 256, 256, 0, stream>>>(wps, pw);
  hipMemsetAsync(h0s, 0, (size_t)2 * ASZ * sizeof(short), stream);
  hipMemsetAsync(o0, 0, (size_t)2 * ASZ * sizeof(short), stream);
  hipMemsetAsync(ctl, 0, 4096, stream);

  hipFuncSetAttribute((const void*)eltm_p, hipFuncAttributeMaxDynamicSharedMemorySize,
                      LDSTOT);
  PP pa;
  pa.x = (const float*)d_in[0];
  pa.pw = pw;
  pa.h0s = h0s;
  pa.h1s = h1s;
  pa.xn0 = xn0;
  pa.hn0 = hn0;
  pa.ch0 = ch0;
  pa.xn1 = xn1;
  pa.hn1 = hn1;
  pa.ch1 = ch1;
  pa.o0 = o0;
  pa.o1 = o1;
  pa.bhi0 = W(3);
  pa.bcho0 = W(9);
  pa.bhi1 = W(14);
  pa.bcho1 = W(20);
  pa.out = out;
  pa.ctl = ctl;
  eltm_p<<<NB_, 512, LDSTOT, stream>>>(pa);

  eltm_kLN<<<16384, 256, 0, stream>>>(out, W(23), W(24));
#undef W
}

// Round 15
// 20961.711 us; speedup vs baseline: 2.9744x; 2.9744x over previous
//
#include <hip/hip_runtime.h>
#include <hip/hip_bf16.h>

#define S_ 512
#define B_ 128
#define D_ 128
#define H_ 512
#define NB_ 256

// ---- packed f16 2-plane weight layout (shorts) ----
#define PK_SA 159744
#define PK_B  5111808
#define PK_BS 98304
#define PK_C  8257536
#define PK_CS 65536
#define PK_TOT 10354688
#define APLANE 65536
#define ASZ    131072   // 2*APLANE

#define SC1 4.8828125e-4f          // 2^-11
#define SC2 2.384185791015625e-7f  // 2^-22

typedef short bf16x8 __attribute__((ext_vector_type(8)));  // generic 16B short container
typedef _Float16 f16x8 __attribute__((ext_vector_type(8)));
typedef int i32x4 __attribute__((ext_vector_type(4)));
typedef float f32x4 __attribute__((ext_vector_type(4)));

__device__ __forceinline__ float sigf(float x) { return 1.0f / (1.0f + expf(-x)); }

// plain cached 16B load
__device__ __forceinline__ i32x4 ldg(const short* p) {
  i32x4 o;
  asm volatile("global_load_dwordx4 %0, %1, off" : "=v"(o) : "v"(p));
  return o;
}
#define VMDRAIN()                                    \
  do {                                               \
    asm volatile("s_waitcnt vmcnt(0)" ::: "memory"); \
    __builtin_amdgcn_sched_barrier(0);               \
  } while (0)

// f16 2-plane split-store / gather (local-XCD L2 visibility only)
__device__ __forceinline__ void st2(short* buf, int idx, float v) {
  _Float16 h0 = (_Float16)v;
  float r1 = (v - (float)h0) * 2048.0f;
  _Float16 h1 = (_Float16)r1;
  buf[idx] = __builtin_bit_cast(short, h0);
  buf[idx + APLANE] = __builtin_bit_cast(short, h1);
}
__device__ __forceinline__ float ld2p(const short* buf, int idx) {
  float a = (float)__builtin_bit_cast(_Float16, buf[idx]);
  float b = (float)__builtin_bit_cast(_Float16, buf[idx + APLANE]);
  return a + b * SC1;
}

#define MFMAH(a, b, c) __builtin_amdgcn_mfma_f32_16x16x32_f16(a, b, c, 0, 0, 0)
#define BC16(x) __builtin_bit_cast(f16x8, x)

__device__ __forceinline__ void mac4(f32x4& c0, f32x4& c1, f32x4& c2, const f16x8& a0,
                                     const f16x8& a1, const f16x8& w0, const f16x8& w1) {
  c0 = MFMAH(a0, w0, c0);
  c1 = MFMAH(a0, w1, c1);
  c1 = MFMAH(a1, w0, c1);
  c2 = MFMAH(a1, w1, c2);
}
__device__ __forceinline__ f32x4 fin3(const f32x4& c0, const f32x4& c1,
                                      const f32x4& c2) {
  f32x4 o;
#pragma unroll
  for (int e = 0; e < 4; ++e) o[e] = c0[e] + SC1 * c1[e] + SC2 * c2[e];
  return o;
}

// GEMV slab: A 2-plane f16 activations (local L2), W packed fragment-ordered stream.
// Per kchunk: W chunk = 2KB contiguous (2 planes x 1KB); lane offset lo = r*32+g*8.
__device__ __forceinline__ void unitP(f32x4& c0, f32x4& c1, f32x4& c2,
                                      const short* aBase, const short* slab, int nks,
                                      int lo) {
  for (int q = 0; q < nks; q += 4) {
    i32x4 A0[4], A1[4], W0[4], W1[4];
#pragma unroll
    for (int u = 0; u < 4; ++u) {
      const short* wp = slab + (size_t)(q + u) * 1024 + lo;
      W0[u] = ldg(wp);
      W1[u] = ldg(wp + 512);
      const short* ap = aBase + (q + u) * 32;
      A0[u] = ldg(ap);
      A1[u] = ldg(ap + APLANE);
    }
    VMDRAIN();
#pragma unroll
    for (int u = 0; u < 4; ++u)
      mac4(c0, c1, c2, BC16(A0[u]), BC16(A1[u]), BC16(W0[u]), BC16(W1[u]));
  }
}

// x-part (4 kchunks of fp32 x, split on the fly)
__device__ __forceinline__ void unitPx(f32x4& c0, f32x4& c1, f32x4& c2,
                                       const float* xRow, const short* slab, int lo) {
  i32x4 W0[4], W1[4];
  f16x8 A0[4], A1[4];
#pragma unroll
  for (int u = 0; u < 4; ++u) {
    const short* wp = slab + (size_t)u * 1024 + lo;
    W0[u] = ldg(wp);
    W1[u] = ldg(wp + 512);
#pragma unroll
    for (int e = 0; e < 8; ++e) {
      float v = xRow[u * 32 + e];
      _Float16 h0 = (_Float16)v;
      A0[u][e] = h0;
      A1[u][e] = (_Float16)((v - (float)h0) * 2048.0f);
    }
  }
  VMDRAIN();
#pragma unroll
  for (int u = 0; u < 4; ++u) mac4(c0, c1, c2, A0[u], A1[u], BC16(W0[u]), BC16(W1[u]));
}

// ---- atomics (agent scope, relaxed, monotonic) ----
__device__ __forceinline__ unsigned int afa(unsigned int* p) {
  return __hip_atomic_fetch_add(p, 1u, __ATOMIC_RELAXED, __HIP_MEMORY_SCOPE_AGENT);
}
__device__ __forceinline__ unsigned int ald(const unsigned int* p) {
  return __hip_atomic_load(p, __ATOMIC_RELAXED, __HIP_MEMORY_SCOPE_AGENT);
}

// XCD-local barrier: ctl[32+32*x]=arrivals, ctl[48+32*x]=generation (monotonic)
__device__ __forceinline__ void gbarX(unsigned int* ctl, int xcd, unsigned int bt,
                                      unsigned int m) {
  asm volatile("s_waitcnt vmcnt(0) lgkmcnt(0)" ::: "memory");
  __syncthreads();
  if (threadIdx.x == 0) {
    unsigned int o = afa(&ctl[32 + 32 * xcd]);
    if (o == m * bt - 1)
      afa(&ctl[48 + 32 * xcd]);
    else
      while (ald(&ctl[48 + 32 * xcd]) < bt) __builtin_amdgcn_s_sleep(2);
  }
  __syncthreads();
  asm volatile("buffer_inv sc0" ::: "memory");  // vL1-only invalidate (same-XCD L2 is truth)
  __builtin_amdgcn_sched_barrier(0);
}

struct PP {
  const float* x;
  const short* pw;
  short* h0s;
  short* h1s;
  short* xn0;
  short* hn0;
  short* ch0;
  short* xn1;
  short* hn1;
  short* ch1;
  short* o0;
  short* o1;
  const float* bhi0;
  const float* bcho0;
  const float* bhi1;
  const float* bcho1;
  float* out;
  unsigned int* ctl;
};

__global__ __launch_bounds__(512, 1) void eltm_p(PP p) {
  extern __shared__ char smem[];
  float* ldsF = (float*)smem;  // phase scratch (8KB max)
  unsigned int* shI = (unsigned int*)(smem + 16384);
  const int tid = threadIdx.x;
  const int lane = tid & 63;
  const int w = tid >> 6;
  const int r = lane & 15;
  const int g = lane >> 4;
  const int lo = r * 32 + g * 8;
  const f32x4 z = {0.f, 0.f, 0.f, 0.f};

  unsigned int xcd;
  asm volatile("s_getreg_b32 %0, hwreg(HW_REG_XCC_ID)" : "=s"(xcd));
  xcd &= 7;
  const int sgx = ((int)xcd) << 2;  // slab stagger offset per XCD

  // self-organize + grid start barrier (all NB_ co-resident: 1 block/CU via LDS)
  if (tid == 0) {
    shI[0] = afa(&p.ctl[xcd]);  // slot within XCD
    unsigned int o = afa(&p.ctl[8]);
    if (o == NB_ - 1)
      __hip_atomic_store(&p.ctl[9], 1u, __ATOMIC_RELAXED, __HIP_MEMORY_SCOPE_AGENT);
    while (ald(&p.ctl[9]) == 0) __builtin_amdgcn_s_sleep(2);
    shI[1] = ald(&p.ctl[xcd]);  // m = blocks on this XCD
  }
  __syncthreads();
  const int slot = shI[0];
  const unsigned int m = shI[1];
  asm volatile("buffer_inv sc0" ::: "memory");

  const int row0 = (int)xcd * 16;            // slice rows [row0, row0+16)
  const int aoff = (row0 + r) * H_ + g * 8;  // A-fragment lane base (plane 0)
  static const int preW[8] = {0, 20480, 40960, 45056, 61440, 94208, 126976, 143360};

  unsigned int bt = 0;
  for (int i = 0; i <= S_; ++i) {
    const int do0 = i < S_;
    const int do1 = i >= 1;
    const float* xr = p.x + ((size_t)i * B_ + row0 + r) * D_ + g * 8;

    // ================= phase A =================
    for (int t = slot; t < 32; t += (int)m) {
      const int s = (t + sgx) & 31;
      const short* slabA = p.pw + (size_t)s * PK_SA;
      const int n = s * 16 + r;
      f32x4 c0 = z, c1 = z, c2 = z;
      f32x4 fin = z;
      switch (w) {
        case 0:
        case 1:
          if (do0) {
            const short* sl = slabA + preW[w];
            unitPx(c0, c1, c2, xr, sl, lo);
            unitP(c0, c1, c2, p.h0s + aoff, sl + 4096, 16, lo);
            fin = fin3(c0, c1, c2);
          }
          break;
        case 2:
          if (do0) {
            unitPx(c0, c1, c2, xr, slabA + preW[2], lo);
            fin = fin3(c0, c1, c2);
#pragma unroll
            for (int e = 0; e < 4; ++e)
              st2(p.xn0, (row0 + g * 4 + e) * H_ + n, tanhf(fin[e]));
          }
          break;
        case 3:
          if (do0) {
            unitP(c0, c1, c2, p.h0s + aoff, slabA + preW[3], 16, lo);
            fin = fin3(c0, c1, c2);
#pragma unroll
            for (int e = 0; e < 4; ++e)
              st2(p.hn0, (row0 + g * 4 + e) * H_ + n, tanhf(fin[e]));
          }
          break;
        case 4:
        case 5:
          if (do1) {
            const short* sl = slabA + preW[w];
            unitP(c0, c1, c2, p.h0s + aoff, sl, 16, lo);
            unitP(c0, c1, c2, p.h1s + aoff, sl + 16384, 16, lo);
            fin = fin3(c0, c1, c2);
          }
          break;
        case 6:
          if (do1) {
            unitP(c0, c1, c2, p.h0s + aoff, slabA + preW[6], 16, lo);
            fin = fin3(c0, c1, c2);
#pragma unroll
            for (int e = 0; e < 4; ++e)
              st2(p.xn1, (row0 + g * 4 + e) * H_ + n, tanhf(fin[e]));
          }
          break;
        default:
          if (do1) {
            unitP(c0, c1, c2, p.h1s + aoff, slabA + preW[7], 16, lo);
            fin = fin3(c0, c1, c2);
#pragma unroll
            for (int e = 0; e < 4; ++e)
              st2(p.hn1, (row0 + g * 4 + e) * H_ + n, tanhf(fin[e]));
          }
          break;
      }
      if ((w == 1 && do0) || (w == 5 && do1)) {
#pragma unroll
        for (int e = 0; e < 4; ++e)
          ldsF[(w == 5 ? 256 : 0) + (g * 4 + e) * 16 + r] = fin[e];
      }
      __syncthreads();
      if (w == 0 && do0) {
        const float bi = p.bhi0[n], bh = p.bhi0[512 + n];
#pragma unroll
        for (int e = 0; e < 4; ++e) {
          float hgv = ldsF[(g * 4 + e) * 16 + r];
          st2(p.ch0, (row0 + g * 4 + e) * H_ + n, sigf(fin[e] + bi) * tanhf(hgv + bh));
        }
      }
      if (w == 4 && do1) {
        const float bi = p.bhi1[n], bh = p.bhi1[512 + n];
#pragma unroll
        for (int e = 0; e < 4; ++e) {
          float hgv = ldsF[256 + (g * 4 + e) * 16 + r];
          st2(p.ch1, (row0 + g * 4 + e) * H_ + n, sigf(fin[e] + bi) * tanhf(hgv + bh));
        }
      }
      __syncthreads();
    }
    ++bt;
    gbarX(p.ctl, xcd, bt, m);

    // ================= phase B =================
    for (int t = slot; t < 32; t += (int)m) {
      const int s = (t + sgx) & 31;
      const int L = w >> 2;
      const int tt = w & 3;
      const int ok = L ? do1 : do0;
      const int n = s * 16 + r;
      if (ok) {
        f32x4 c0 = z, c1 = z, c2 = z;
        const short* slab = p.pw + PK_B + (size_t)s * PK_BS + (size_t)L * 49152;
        const short* xn = L ? p.xn1 : p.xn0;
        const short* hn = L ? p.hn1 : p.hn0;
        const short* ch = L ? p.ch1 : p.ch0;
        if (tt == 0)
          unitP(c0, c1, c2, xn + aoff, slab, 16, lo);
        else if (tt == 1)
          unitP(c0, c1, c2, hn + aoff, slab + 16384, 16, lo);
        else if (tt == 2)
          unitP(c0, c1, c2, ch + aoff, slab + 32768, 8, lo);
        else
          unitP(c0, c1, c2, ch + aoff + 256, slab + 40960, 8, lo);
        f32x4 fin = fin3(c0, c1, c2);
#pragma unroll
        for (int e = 0; e < 4; ++e) ldsF[w * 256 + (g * 4 + e) * 16 + r] = fin[e];
      }
      __syncthreads();
      if ((w == 0 && do0) || (w == 4 && do1)) {
        const float bc = (w == 4 ? p.bcho1 : p.bcho0)[n];
        short* o = w == 4 ? p.o1 : p.o0;
#pragma unroll
        for (int e = 0; e < 4; ++e) {
          const int q = (g * 4 + e) * 16 + r;
          float sum = ldsF[w * 256 + q] + ldsF[(w + 1) * 256 + q] +
                      ldsF[(w + 2) * 256 + q] + ldsF[(w + 3) * 256 + q];
          st2(o, (row0 + g * 4 + e) * H_ + n, sigf(sum + bc));
        }
      }
      __syncthreads();
    }
    ++bt;
    gbarX(p.ctl, xcd, bt, m);

    // ================= phase C =================
    for (int t = slot; t < 32; t += (int)m) {
      const int s = (t + sgx) & 31;
      const int L = s & 1;
      const int ok = L ? do1 : do0;
      const int u = w >> 1;
      const int h = w & 1;
      if (ok) {
        f32x4 c0 = z, c1 = z, c2 = z;
        const short* slab =
            p.pw + PK_C + (size_t)s * PK_CS + (size_t)u * 16384 + (size_t)h * 8192;
        const short* o = L ? p.o1 : p.o0;
        unitP(c0, c1, c2, o + aoff + h * 256, slab, 8, lo);
        f32x4 fin = fin3(c0, c1, c2);
#pragma unroll
        for (int e = 0; e < 4; ++e) ldsF[w * 256 + (g * 4 + e) * 16 + r] = fin[e];
      }
      __syncthreads();
      if ((w == 0 || w == 4) && ok) {
        const int j = (w == 0) ? (s >> 1) : (16 + (s >> 1));
        const int ub = (w == 0) ? 0 : 4;
        const short* xn = L ? p.xn1 : p.xn0;
        const short* hn = L ? p.hn1 : p.hn0;
        const short* ch = L ? p.ch1 : p.ch0;
        short* hs = L ? p.h1s : p.h0s;
#pragma unroll
        for (int e = 0; e < 4; ++e) {
          const int q = (g * 4 + e) * 16 + r;
          const float av = ldsF[(ub + 0) * 256 + q] + ldsF[(ub + 1) * 256 + q];
          const float bv = ldsF[(ub + 2) * 256 + q] + ldsF[(ub + 3) * 256 + q];
          const int idx = (row0 + g * 4 + e) * H_ + j * 16 + r;
          const float hval = av * ld2p(xn, idx) + bv * ld2p(hn, idx) +
                             (1.f - av - bv) * ld2p(ch, idx);
          st2(hs, idx, hval);
          if (L) p.out[(size_t)(i - 1) * B_ * H_ + idx] = hval;
        }
      }
      __syncthreads();
    }
    ++bt;
    gbarX(p.ctl, xcd, bt, m);
  }
}

// ---------------- prologue: repack fp32 weights -> packed f16 2-plane fragment stream ----------------
struct WP18 {
  const float* m[18];
};
__global__ void repack(WP18 wp, short* pw) {
  const long long t8 = (long long)blockIdx.x * 256 + threadIdx.x;
  const long long id = t8 * 8;
  if (id >= (long long)PK_TOT) return;
  int mat, row, kb, p;
  if (id < (long long)PK_B) {
    int s = (int)(id / PK_SA), rem = (int)(id % PK_SA);
    const int pre[9] = {0, 20480, 40960, 45056, 61440, 94208, 126976, 143360, 159744};
    int w = 0;
    while (rem >= pre[w + 1]) ++w;
    int off = rem - pre[w];
    int c = off >> 10, r2 = off & 1023;
    p = r2 >> 9;
    int q2 = r2 & 511, rr = q2 >> 5, gg = (q2 & 31) >> 3;
    int kin = c * 32 + gg * 8;
    switch (w) {
      case 0:
      case 1:
        row = (w == 1 ? 512 : 0) + s * 16 + rr;
        if (kin < 128) { mat = 0; kb = kin; } else { mat = 1; kb = kin - 128; }
        break;
      case 2: mat = 2; row = s * 16 + rr; kb = kin; break;
      case 3: mat = 3; row = s * 16 + rr; kb = kin; break;
      case 4:
      case 5:
        row = (w == 5 ? 512 : 0) + s * 16 + rr;
        if (kin < 512) { mat = 9; kb = kin; } else { mat = 10; kb = kin - 512; }
        break;
      case 6: mat = 11; row = s * 16 + rr; kb = kin; break;
      default: mat = 12; row = s * 16 + rr; kb = kin; break;
    }
  } else if (id < (long long)PK_C) {
    int rem = (int)(id - PK_B);
    int s = rem / PK_BS, r2 = rem % PK_BS;
    int tt = r2 / 16384, off = r2 % 16384;
    int c = off >> 10, r3 = off & 1023;
    p = r3 >> 9;
    int q2 = r3 & 511, rr = q2 >> 5, gg = (q2 & 31) >> 3;
    const int mats[6] = {4, 5, 6, 13, 14, 15};
    mat = mats[tt];
    row = s * 16 + rr;
    kb = c * 32 + gg * 8;
  } else {
    int rem = (int)(id - PK_C);
    int s = rem / PK_CS, r2 = rem % PK_CS;
    int u = r2 / 16384, off = r2 % 16384;
    int c = off >> 10, r3 = off & 1023;
    p = r3 >> 9;
    int q2 = r3 & 511, rr = q2 >> 5, gg = (q2 & 31) >> 3;
    int L = s & 1, j = (u < 2) ? (s >> 1) : (16 + (s >> 1));
    mat = (L ? 16 : 7) + (u & 1);
    row = j * 16 + rr;
    kb = c * 32 + gg * 8;
  }
  const int KS = (mat == 0 || mat == 2) ? 128 : 512;
  const float* src = wp.m[mat] + (long long)row * KS + kb;
  bf16x8 o8;
#pragma unroll
  for (int e = 0; e < 8; ++e) {
    float v = src[e];
    _Float16 h0 = (_Float16)v;
    short sv;
    if (p == 0) {
      sv = __builtin_bit_cast(short, h0);
    } else {
      _Float16 h1 = (_Float16)((v - (float)h0) * 2048.0f);
      sv = __builtin_bit_cast(short, h1);
    }
    o8[e] = sv;
  }
  *(bf16x8*)(pw + id) = o8;
}

// ---------------- final: in-place sinrelu + LayerNorm over H on d_out ----------------
__global__ void eltm_kLN(float* __restrict__ out, const float* __restrict__ g,
                         const float* __restrict__ bta) {
  const int row = blockIdx.x * 4 + (threadIdx.x >> 6);
  const int lane = threadIdx.x & 63;
  float* r = out + (size_t)row * H_;
  float v[8];
  float s = 0.f, s2 = 0.f;
#pragma unroll
  for (int i = 0; i < 8; ++i) {
    float x = r[lane + i * 64];
    float sv = (x >= 0.f) ? (x + sinf(x)) : 0.f;
    v[i] = sv;
    s += sv;
    s2 += sv * sv;
  }
#pragma unroll
  for (int m = 1; m < 64; m <<= 1) {
    s += __shfl_xor(s, m);
    s2 += __shfl_xor(s2, m);
  }
  const float mean = s * (1.f / 512.f);
  const float var = s2 * (1.f / 512.f) - mean * mean;
  const float rstd = rsqrtf(var + 1e-5f);
#pragma unroll
  for (int i = 0; i < 8; ++i) {
    const int c = lane + i * 64;
    r[c] = (v[i] - mean) * rstd * g[c] + bta[c];
  }
}

extern "C" void kernel_launch(void* const* d_in, const int* in_sizes, int n_in,
                              void* d_out, int out_size, void* d_ws, size_t ws_size,
                              hipStream_t stream) {
#define W(i) ((const float*)d_in[i])
  short* pw = (short*)d_ws;
  short* acts = pw + (size_t)PK_TOT;
  short* h0s = acts;
  short* h1s = acts + ASZ;
  short* xn0 = acts + 2 * ASZ;
  short* hn0 = acts + 3 * ASZ;
  short* ch0 = acts + 4 * ASZ;
  short* xn1 = acts + 5 * ASZ;
  short* hn1 = acts + 6 * ASZ;
  short* ch1 = acts + 7 * ASZ;
  short* o0 = acts + 8 * ASZ;
  short* o1 = acts + 9 * ASZ;
  unsigned int* ctl = (unsigned int*)(acts + 10 * (size_t)ASZ);
  float* out = (float*)d_out;

  WP18 wps;
  const int srcIdx[18] = {1,  2,  4,  5,  6,  7,  8,  10, 11,
                          12, 13, 15, 16, 17, 18, 19, 21, 22};
  for (int i = 0; i < 18; ++i) wps.m[i] = W(srcIdx[i]);

  repack<<<PK_TOT / 8 / 256, 256, 0, stream>>>(wps, pw);
  hipMemsetAsync(h0s, 0, (size_t)2 * ASZ * sizeof(short), stream);
  hipMemsetAsync(ctl, 0, 2048, stream);

  hipFuncSetAttribute((const void*)eltm_p, hipFuncAttributeMaxDynamicSharedMemorySize,
                      98304);
  PP pa;
  pa.x = (const float*)d_in[0];
  pa.pw = pw;
  pa.h0s = h0s;
  pa.h1s = h1s;
  pa.xn0 = xn0;
  pa.hn0 = hn0;
  pa.ch0 = ch0;
  pa.xn1 = xn1;
  pa.hn1 = hn1;
  pa.ch1 = ch1;
  pa.o0 = o0;
  pa.o1 = o1;
  pa.bhi0 = W(3);
  pa.bcho0 = W(9);
  pa.bhi1 = W(14);
  pa.bcho1 = W(20);
  pa.out = out;
  pa.ctl = ctl;
  eltm_p<<<NB_, 512, 98304, stream>>>(pa);

  eltm_kLN<<<16384, 256, 0, stream>>>(out, W(23), W(24));
#undef W
}